// Round 1
// baseline (1111.990 us; speedup 1.0000x reference)
//
#include <hip/hip_runtime.h>
#include <hip/hip_bf16.h>

#define CH 64  // all channel dims are 64

// deg accumulate: one thread per edge, atomicAdd 1.0 to deg[dst]
__global__ void deg_count_kernel(const int* __restrict__ dst, float* __restrict__ deg, int E) {
    int e = blockIdx.x * blockDim.x + threadIdx.x;
    if (e < E) atomicAdd(&deg[dst[e]], 1.0f);
}

// dis[i] = rsqrt(deg[i] + 1)   (+1 = self loop; deg buffer was memset to 0)
__global__ void dis_kernel(float* __restrict__ deg, int n) {
    int i = blockIdx.x * blockDim.x + threadIdx.x;
    if (i < n) {
        float d = deg[i] + 1.0f;
        deg[i] = rsqrtf(d);  // d >= 1 always
    }
}

// Y[r,c] = sum_k X[r,k] * W[k,c].  One thread per output element; a wave
// covers one row (lane = c) so X[r,k] is a broadcast load and W is LDS.
__global__ void gemm64_kernel(const float* __restrict__ X, const float* __restrict__ W,
                              float* __restrict__ Y, int n) {
    __shared__ float Ws[CH * CH];
    for (int i = threadIdx.x; i < CH * CH; i += blockDim.x) Ws[i] = W[i];
    __syncthreads();
    int idx = blockIdx.x * blockDim.x + threadIdx.x;
    int r = idx >> 6;
    int c = idx & 63;
    if (r >= n) return;
    const float* xr = X + r * CH;
    float acc = 0.0f;
#pragma unroll
    for (int k = 0; k < CH; ++k) acc += xr[k] * Ws[k * CH + c];
    Y[idx] = acc;
}

// One wave per edge, lane = channel. agg[dst,c] += xw[src,c]*dis[src]*dis[dst]
__global__ void scatter_kernel(const float* __restrict__ xw, const int* __restrict__ src,
                               const int* __restrict__ dst, const float* __restrict__ dis,
                               float* __restrict__ agg, int E) {
    int wid = (blockIdx.x * blockDim.x + threadIdx.x) >> 6;
    int lane = threadIdx.x & 63;
    if (wid >= E) return;
    int s = src[wid];
    int d = dst[wid];
    float en = dis[s] * dis[d];
    atomicAdd(&agg[d * CH + lane], xw[s * CH + lane] * en);
}

// out[r,c] = relu(agg[r,c] + xw[r,c]*dis[r]^2 + b[c])   (self-loop folded in)
__global__ void finalize_kernel(const float* __restrict__ agg, const float* __restrict__ xw,
                                const float* __restrict__ dis, const float* __restrict__ b,
                                float* __restrict__ out, int n) {
    int idx = blockIdx.x * blockDim.x + threadIdx.x;
    if (idx >= n * CH) return;
    int r = idx >> 6;
    int c = idx & 63;
    float di = dis[r];
    float v = agg[idx] + xw[idx] * di * di + b[c];
    out[idx] = fmaxf(v, 0.0f);
}

// grid-stride sum + sumsq -> atomicAdd into partials[0..1]
__global__ void reduce_kernel(const float* __restrict__ x, int n, float* __restrict__ partials) {
    float s = 0.0f, sq = 0.0f;
    for (int i = blockIdx.x * blockDim.x + threadIdx.x; i < n; i += gridDim.x * blockDim.x) {
        float v = x[i];
        s += v;
        sq += v * v;
    }
#pragma unroll
    for (int off = 32; off > 0; off >>= 1) {
        s += __shfl_down(s, off, 64);
        sq += __shfl_down(sq, off, 64);
    }
    __shared__ float ls[4], lq[4];
    int wid = threadIdx.x >> 6;
    int lane = threadIdx.x & 63;
    if (lane == 0) { ls[wid] = s; lq[wid] = sq; }
    __syncthreads();
    if (threadIdx.x == 0) {
        float ts = 0.0f, tq = 0.0f;
        for (int w = 0; w < 4; ++w) { ts += ls[w]; tq += lq[w]; }
        atomicAdd(&partials[0], ts);
        atomicAdd(&partials[1], tq);
    }
}

__global__ void norm_kernel(float* __restrict__ x, int n, const float* __restrict__ partials,
                            const float* __restrict__ lnw, const float* __restrict__ lnb) {
    int i = blockIdx.x * blockDim.x + threadIdx.x;
    if (i >= n) return;
    float inv_n = 1.0f / (float)n;
    float mean = partials[0] * inv_n;
    float var = partials[1] * inv_n - mean * mean;
    float scale = rsqrtf(var + 1e-5f) * lnw[0];
    x[i] = (x[i] - mean) * scale + lnb[0];
}

extern "C" void kernel_launch(void* const* d_in, const int* in_sizes, int n_in,
                              void* d_out, int out_size, void* d_ws, size_t ws_size,
                              hipStream_t stream) {
    const float* X   = (const float*)d_in[0];
    const int*   edg = (const int*)d_in[1];   // [2,E] row-major: src then dst
    const float* W1  = (const float*)d_in[2];
    const float* b1  = (const float*)d_in[3];
    const float* W2  = (const float*)d_in[4];
    const float* b2  = (const float*)d_in[5];
    const float* lnw = (const float*)d_in[6];
    const float* lnb = (const float*)d_in[7];
    float* out = (float*)d_out;

    const int N = in_sizes[0] / CH;       // 100000
    const int E = in_sizes[1] / 2;        // 1600000
    const int NC = N * CH;                // 6.4M

    const int* srcp = edg;
    const int* dstp = edg + E;

    float* ws  = (float*)d_ws;
    float* dis = ws;                      // N floats (deg then dis, in place)
    float* xw  = ws + N;                  // 64N floats (xw1, later xw2)
    float* agg = ws + N + NC;             // 64N floats (agg1 -> h -> agg2)
    float* partials = ws + N + 2 * NC;    // 2 floats

    const int B = 256;
    dim3 blk(B);

    // ---- degree / norm ----
    hipMemsetAsync(dis, 0, N * sizeof(float), stream);
    hipMemsetAsync(agg, 0, (size_t)NC * sizeof(float), stream);
    hipMemsetAsync(partials, 0, 2 * sizeof(float), stream);
    deg_count_kernel<<<(E + B - 1) / B, blk, 0, stream>>>(dstp, dis, E);
    dis_kernel<<<(N + B - 1) / B, blk, 0, stream>>>(dis, N);

    // ---- layer 1 ----
    gemm64_kernel<<<(NC + B - 1) / B, blk, 0, stream>>>(X, W1, xw, N);
    {
        long long threads = (long long)E * 64;
        scatter_kernel<<<(unsigned)((threads + B - 1) / B), blk, 0, stream>>>(xw, srcp, dstp, dis, agg, E);
    }
    // h written in place over agg
    finalize_kernel<<<(NC + B - 1) / B, blk, 0, stream>>>(agg, xw, dis, b1, agg, N);

    // ---- layer 2 ----
    gemm64_kernel<<<(NC + B - 1) / B, blk, 0, stream>>>(agg, W2, xw, N);  // xw2 overwrites xw1
    hipMemsetAsync(agg, 0, (size_t)NC * sizeof(float), stream);           // ordered after gemm
    {
        long long threads = (long long)E * 64;
        scatter_kernel<<<(unsigned)((threads + B - 1) / B), blk, 0, stream>>>(xw, srcp, dstp, dis, agg, E);
    }
    finalize_kernel<<<(NC + B - 1) / B, blk, 0, stream>>>(agg, xw, dis, b2, out, N);

    // ---- graph layernorm ----
    reduce_kernel<<<2048, blk, 0, stream>>>(out, NC, partials);
    norm_kernel<<<(NC + B - 1) / B, blk, 0, stream>>>(out, NC, partials, lnw, lnb);
}

// Round 2
// 619.680 us; speedup vs baseline: 1.7945x; 1.7945x over previous
//
#include <hip/hip_runtime.h>

#define CH 64  // IN_C = HID_C = OUT_C = 64

// ---------- CSR build ----------

// histogram of dst into deg (int)
__global__ void deg_count_kernel(const int* __restrict__ dst, int* __restrict__ deg, int E) {
    int e = blockIdx.x * blockDim.x + threadIdx.x;
    if (e < E) atomicAdd(&deg[dst[e]], 1);
}

// dis[i] = rsqrt(deg[i] + 1)  (self loop adds 1; deg >= 0)
__global__ void dis_kernel(const int* __restrict__ deg, float* __restrict__ dis, int n) {
    int i = blockIdx.x * blockDim.x + threadIdx.x;
    if (i < n) dis[i] = rsqrtf((float)deg[i] + 1.0f);
}

// per-block (1024-elem) exclusive scan of rs in place; block totals to bsum
__global__ void scan_block_kernel(int* __restrict__ rs, int* __restrict__ bsum, int n) {
    __shared__ int tmp[1024];
    int t = threadIdx.x;
    int i = blockIdx.x * 1024 + t;
    int v = (i < n) ? rs[i] : 0;
    tmp[t] = v;
    __syncthreads();
    for (int off = 1; off < 1024; off <<= 1) {
        int a = (t >= off) ? tmp[t - off] : 0;
        __syncthreads();
        tmp[t] += a;
        __syncthreads();
    }
    if (i < n) rs[i] = tmp[t] - v;  // exclusive
    if (t == 1023) bsum[blockIdx.x] = tmp[1023];
}

// single-block exclusive scan of bsum (nb <= 1024)
__global__ void scan_top_kernel(int* __restrict__ bsum, int nb) {
    __shared__ int tmp[1024];
    int t = threadIdx.x;
    int v = (t < nb) ? bsum[t] : 0;
    tmp[t] = v;
    __syncthreads();
    for (int off = 1; off < 1024; off <<= 1) {
        int a = (t >= off) ? tmp[t - off] : 0;
        __syncthreads();
        tmp[t] += a;
        __syncthreads();
    }
    if (t < nb) bsum[t] = tmp[t] - v;
}

__global__ void scan_add_kernel(int* __restrict__ rs, const int* __restrict__ bsum, int n) {
    int i = blockIdx.x * blockDim.x + threadIdx.x;
    if (i < n) rs[i] += bsum[i >> 10];
}

// fill col via cursor (= rs, holds row_start); afterwards rs[i] == row_end[i]
__global__ void fill_csr_kernel(const int* __restrict__ src, const int* __restrict__ dst,
                                int* __restrict__ cursor, int* __restrict__ col, int E) {
    int e = blockIdx.x * blockDim.x + threadIdx.x;
    if (e < E) {
        int d = dst[e];
        int pos = atomicAdd(&cursor[d], 1);
        col[pos] = src[e];
    }
}

// ---------- compute ----------

// Y[r,c] = (sum_k X[r,k] * W[k,c]) * dis[r].  One thread per output elem;
// wave = one row (lane = c): X loads broadcast (float4), W in LDS stride-1.
__global__ void gemm64_scaled_kernel(const float* __restrict__ X, const float* __restrict__ W,
                                     const float* __restrict__ dis, float* __restrict__ Y, int n) {
    __shared__ float Ws[CH * CH];
    for (int i = threadIdx.x; i < CH * CH; i += blockDim.x) Ws[i] = W[i];
    __syncthreads();
    int idx = blockIdx.x * blockDim.x + threadIdx.x;
    int r = idx >> 6;
    int c = idx & 63;
    if (r >= n) return;
    const float4* xr4 = (const float4*)(X + r * CH);
    float acc = 0.0f;
#pragma unroll
    for (int k4 = 0; k4 < CH / 4; ++k4) {
        float4 x = xr4[k4];
        acc += x.x * Ws[(4 * k4 + 0) * CH + c];
        acc += x.y * Ws[(4 * k4 + 1) * CH + c];
        acc += x.z * Ws[(4 * k4 + 2) * CH + c];
        acc += x.w * Ws[(4 * k4 + 3) * CH + c];
    }
    Y[idx] = acc * dis[r];
}

// one wave per node, lane = channel:
// out[d,c] = relu( dis[d] * (sum_{e in row d} xws[col[e],c] + xws[d,c]) + b[c] )
__global__ void gather_kernel(const float* __restrict__ xws, const int* __restrict__ col,
                              const int* __restrict__ row_end, const float* __restrict__ dis,
                              const float* __restrict__ b, float* __restrict__ out, int n) {
    int wid = (blockIdx.x * blockDim.x + threadIdx.x) >> 6;
    int lane = threadIdx.x & 63;
    if (wid >= n) return;
    int end = row_end[wid];
    int beg = (wid > 0) ? row_end[wid - 1] : 0;
    float acc = 0.0f;
    int e = beg;
    for (; e + 3 < end; e += 4) {
        int s0 = col[e], s1 = col[e + 1], s2 = col[e + 2], s3 = col[e + 3];
        float v0 = xws[s0 * CH + lane];
        float v1 = xws[s1 * CH + lane];
        float v2 = xws[s2 * CH + lane];
        float v3 = xws[s3 * CH + lane];
        acc += v0 + v1 + v2 + v3;
    }
    for (; e < end; ++e) acc += xws[col[e] * CH + lane];
    float d = dis[wid];
    float v = d * (acc + xws[wid * CH + lane]) + b[lane];
    out[wid * CH + lane] = fmaxf(v, 0.0f);
}

// ---------- graph layernorm (two-level, no hot atomics) ----------

__global__ void reduce1_kernel(const float* __restrict__ x, int n4,
                               float* __restrict__ sums, float* __restrict__ sqs) {
    const float4* x4 = (const float4*)x;
    float s = 0.0f, sq = 0.0f;
    for (int i = blockIdx.x * blockDim.x + threadIdx.x; i < n4; i += gridDim.x * blockDim.x) {
        float4 v = x4[i];
        s += v.x + v.y + v.z + v.w;
        sq += v.x * v.x + v.y * v.y + v.z * v.z + v.w * v.w;
    }
#pragma unroll
    for (int off = 32; off > 0; off >>= 1) {
        s += __shfl_down(s, off, 64);
        sq += __shfl_down(sq, off, 64);
    }
    __shared__ float ls[4], lq[4];
    int w = threadIdx.x >> 6;
    if ((threadIdx.x & 63) == 0) { ls[w] = s; lq[w] = sq; }
    __syncthreads();
    if (threadIdx.x == 0) {
        sums[blockIdx.x] = ls[0] + ls[1] + ls[2] + ls[3];
        sqs[blockIdx.x] = lq[0] + lq[1] + lq[2] + lq[3];
    }
}

// single block: reduce 1024 partials, write {scale, offset} so norm is one fma
__global__ void reduce2_kernel(const float* __restrict__ sums, const float* __restrict__ sqs,
                               int nb, float n_total, const float* __restrict__ lnw,
                               const float* __restrict__ lnb, float* __restrict__ so) {
    __shared__ float ls[16], lq[16];
    int t = threadIdx.x;
    float s = (t < nb) ? sums[t] : 0.0f;
    float sq = (t < nb) ? sqs[t] : 0.0f;
#pragma unroll
    for (int off = 32; off > 0; off >>= 1) {
        s += __shfl_down(s, off, 64);
        sq += __shfl_down(sq, off, 64);
    }
    int w = t >> 6;
    if ((t & 63) == 0) { ls[w] = s; lq[w] = sq; }
    __syncthreads();
    if (t == 0) {
        float ts = 0.0f, tq = 0.0f;
        for (int i = 0; i < 16; ++i) { ts += ls[i]; tq += lq[i]; }
        float mean = ts / n_total;
        float var = tq / n_total - mean * mean;
        float scale = rsqrtf(var + 1e-5f) * lnw[0];
        so[0] = scale;
        so[1] = lnb[0] - mean * scale;
    }
}

__global__ void norm_kernel(float* __restrict__ x, int n4, const float* __restrict__ so) {
    int i = blockIdx.x * blockDim.x + threadIdx.x;
    if (i >= n4) return;
    float scale = so[0], off = so[1];
    float4* x4 = (float4*)x;
    float4 v = x4[i];
    v.x = v.x * scale + off;
    v.y = v.y * scale + off;
    v.z = v.z * scale + off;
    v.w = v.w * scale + off;
    x4[i] = v;
}

extern "C" void kernel_launch(void* const* d_in, const int* in_sizes, int n_in,
                              void* d_out, int out_size, void* d_ws, size_t ws_size,
                              hipStream_t stream) {
    const float* X   = (const float*)d_in[0];
    const int*   edg = (const int*)d_in[1];   // [2,E]: src row then dst row
    const float* W1  = (const float*)d_in[2];
    const float* b1  = (const float*)d_in[3];
    const float* W2  = (const float*)d_in[4];
    const float* b2  = (const float*)d_in[5];
    const float* lnw = (const float*)d_in[6];
    const float* lnb = (const float*)d_in[7];
    float* out = (float*)d_out;

    const int N  = in_sizes[0] / CH;   // 100000
    const int E  = in_sizes[1] / 2;    // 1600000
    const int NC = N * CH;             // 6.4M

    const int* srcp = edg;
    const int* dstp = edg + E;

    // workspace layout (4B units)
    int*   rs   = (int*)d_ws;                    // N: deg -> row_start -> row_end
    int*   col  = rs + N;                        // E
    float* dis  = (float*)(col + E);             // N
    float* xws  = dis + N;                       // NC
    float* h    = xws + NC;                      // NC
    int*   bsum = (int*)(h + NC);                // 1024 (scan block sums)
    float* sums = (float*)(bsum + 1024);         // 1024
    float* sqs  = sums + 1024;                   // 1024
    float* so   = sqs + 1024;                    // 2 {scale, offset}

    const int B = 256;
    const int nScanBlk = (N + 1023) / 1024;      // 98

    // ---- CSR build ----
    hipMemsetAsync(rs, 0, (size_t)N * sizeof(int), stream);
    deg_count_kernel<<<(E + B - 1) / B, B, 0, stream>>>(dstp, rs, E);
    dis_kernel<<<(N + B - 1) / B, B, 0, stream>>>(rs, dis, N);
    scan_block_kernel<<<nScanBlk, 1024, 0, stream>>>(rs, bsum, N);
    scan_top_kernel<<<1, 1024, 0, stream>>>(bsum, nScanBlk);
    scan_add_kernel<<<(N + B - 1) / B, B, 0, stream>>>(rs, bsum, N);
    fill_csr_kernel<<<(E + B - 1) / B, B, 0, stream>>>(srcp, dstp, rs, col, E);
    // rs now holds row_end

    // ---- layer 1 ----
    gemm64_scaled_kernel<<<(NC + B - 1) / B, B, 0, stream>>>(X, W1, dis, xws, N);
    gather_kernel<<<(N * 64 + B - 1) / B, B, 0, stream>>>(xws, col, rs, dis, b1, h, N);

    // ---- layer 2 ----
    gemm64_scaled_kernel<<<(NC + B - 1) / B, B, 0, stream>>>(h, W2, dis, xws, N);
    gather_kernel<<<(N * 64 + B - 1) / B, B, 0, stream>>>(xws, col, rs, dis, b2, out, N);

    // ---- graph layernorm ----
    reduce1_kernel<<<1024, B, 0, stream>>>(out, NC / 4, sums, sqs);
    reduce2_kernel<<<1, 1024, 0, stream>>>(sums, sqs, 1024, (float)NC, lnw, lnb, so);
    norm_kernel<<<(NC / 4 + B - 1) / B, B, 0, stream>>>(out, NC / 4, so);
}

// Round 3
// 507.941 us; speedup vs baseline: 2.1892x; 1.2200x over previous
//
#include <hip/hip_runtime.h>
#include <hip/hip_bf16.h>

#define CH 64  // IN_C = HID_C = OUT_C = 64

// ---------- CSR build ----------

// deg histogram + per-edge rank (rank written coalesced)
__global__ void deg_rank_kernel(const int* __restrict__ dst, int* __restrict__ deg,
                                int* __restrict__ rank, int E) {
    int e = blockIdx.x * blockDim.x + threadIdx.x;
    if (e < E) rank[e] = atomicAdd(&deg[dst[e]], 1);
}

// per-block (1024) exclusive scan of rs in place; also emits dis = rsqrt(deg+1)
__global__ void scan_block_kernel(int* __restrict__ rs, int* __restrict__ bsum,
                                  float* __restrict__ dis, int n) {
    __shared__ int tmp[1024];
    int t = threadIdx.x;
    int i = blockIdx.x * 1024 + t;
    int v = (i < n) ? rs[i] : 0;
    if (i < n) dis[i] = rsqrtf((float)v + 1.0f);
    tmp[t] = v;
    __syncthreads();
    for (int off = 1; off < 1024; off <<= 1) {
        int a = (t >= off) ? tmp[t - off] : 0;
        __syncthreads();
        tmp[t] += a;
        __syncthreads();
    }
    if (i < n) rs[i] = tmp[t] - v;  // exclusive
    if (t == 1023) bsum[blockIdx.x] = tmp[1023];
}

// single-block exclusive scan of bsum (nb <= 1024)
__global__ void scan_top_kernel(int* __restrict__ bsum, int nb) {
    __shared__ int tmp[1024];
    int t = threadIdx.x;
    int v = (t < nb) ? bsum[t] : 0;
    tmp[t] = v;
    __syncthreads();
    for (int off = 1; off < 1024; off <<= 1) {
        int a = (t >= off) ? tmp[t - off] : 0;
        __syncthreads();
        tmp[t] += a;
        __syncthreads();
    }
    if (t < nb) bsum[t] = tmp[t] - v;
}

__global__ void scan_add_kernel(int* __restrict__ rs, const int* __restrict__ bsum, int n) {
    int i = blockIdx.x * blockDim.x + threadIdx.x;
    if (i < n) rs[i] += bsum[i >> 10];
}

// pre-addressed fill: no atomics (rank computed in deg pass); rs stays row_start
__global__ void fill_csr_kernel(const int* __restrict__ src, const int* __restrict__ dst,
                                const int* __restrict__ rs, const int* __restrict__ rank,
                                int* __restrict__ col, int E) {
    int e = blockIdx.x * blockDim.x + threadIdx.x;
    if (e < E) col[rs[dst[e]] + rank[e]] = src[e];
}

// ---------- compute ----------

// Y[r,c] = bf16( (sum_k X[r,k] * W[k,c]) * dis[r] ).  Wave = one row (lane = c).
__global__ void gemm64_scaled_kernel(const float* __restrict__ X, const float* __restrict__ W,
                                     const float* __restrict__ dis,
                                     __hip_bfloat16* __restrict__ Y, int n) {
    __shared__ float Ws[CH * CH];
    for (int i = threadIdx.x; i < CH * CH; i += blockDim.x) Ws[i] = W[i];
    __syncthreads();
    int idx = blockIdx.x * blockDim.x + threadIdx.x;
    int r = idx >> 6;
    int c = idx & 63;
    if (r >= n) return;
    const float4* xr4 = (const float4*)(X + r * CH);
    float acc = 0.0f;
#pragma unroll
    for (int k4 = 0; k4 < CH / 4; ++k4) {
        float4 x = xr4[k4];
        acc += x.x * Ws[(4 * k4 + 0) * CH + c];
        acc += x.y * Ws[(4 * k4 + 1) * CH + c];
        acc += x.z * Ws[(4 * k4 + 2) * CH + c];
        acc += x.w * Ws[(4 * k4 + 3) * CH + c];
    }
    Y[idx] = __float2bfloat16(acc * dis[r]);
}

// one wave per node, lane = channel (bf16 gather, fp32 accumulate):
// out[d,c] = relu( dis[d] * (sum_{e in row d} xws[col[e],c] + xws[d,c]) + b[c] )
__global__ void gather_kernel(const __hip_bfloat16* __restrict__ xws, const int* __restrict__ col,
                              const int* __restrict__ rs, const float* __restrict__ dis,
                              const float* __restrict__ b, float* __restrict__ out,
                              int n, int E) {
    int wid = (blockIdx.x * blockDim.x + threadIdx.x) >> 6;
    int lane = threadIdx.x & 63;
    if (wid >= n) return;
    int beg = rs[wid];
    int end = (wid + 1 < n) ? rs[wid + 1] : E;
    float acc = 0.0f;
    int e = beg;
    for (; e + 3 < end; e += 4) {
        int s0 = col[e], s1 = col[e + 1], s2 = col[e + 2], s3 = col[e + 3];
        float v0 = __bfloat162float(xws[s0 * CH + lane]);
        float v1 = __bfloat162float(xws[s1 * CH + lane]);
        float v2 = __bfloat162float(xws[s2 * CH + lane]);
        float v3 = __bfloat162float(xws[s3 * CH + lane]);
        acc += v0 + v1 + v2 + v3;
    }
    for (; e < end; ++e) acc += __bfloat162float(xws[col[e] * CH + lane]);
    float d = dis[wid];
    float v = d * (acc + __bfloat162float(xws[wid * CH + lane])) + b[lane];
    out[wid * CH + lane] = fmaxf(v, 0.0f);
}

// gather + relu + per-block LN partial sums (no atomics; one partial pair per block)
__global__ void gather_stats_kernel(const __hip_bfloat16* __restrict__ xws,
                                    const int* __restrict__ col, const int* __restrict__ rs,
                                    const float* __restrict__ dis, const float* __restrict__ b,
                                    float* __restrict__ out, int n, int E,
                                    float* __restrict__ sums, float* __restrict__ sqs) {
    int wid = (blockIdx.x * blockDim.x + threadIdx.x) >> 6;
    int lane = threadIdx.x & 63;
    float v = 0.0f;
    if (wid < n) {
        int beg = rs[wid];
        int end = (wid + 1 < n) ? rs[wid + 1] : E;
        float acc = 0.0f;
        int e = beg;
        for (; e + 3 < end; e += 4) {
            int s0 = col[e], s1 = col[e + 1], s2 = col[e + 2], s3 = col[e + 3];
            float v0 = __bfloat162float(xws[s0 * CH + lane]);
            float v1 = __bfloat162float(xws[s1 * CH + lane]);
            float v2 = __bfloat162float(xws[s2 * CH + lane]);
            float v3 = __bfloat162float(xws[s3 * CH + lane]);
            acc += v0 + v1 + v2 + v3;
        }
        for (; e < end; ++e) acc += __bfloat162float(xws[col[e] * CH + lane]);
        float d = dis[wid];
        v = fmaxf(d * (acc + __bfloat162float(xws[wid * CH + lane])) + b[lane], 0.0f);
        out[wid * CH + lane] = v;
    }
    // block reduction of sum / sumsq
    float s = v, sq = v * v;
#pragma unroll
    for (int off = 32; off > 0; off >>= 1) {
        s += __shfl_down(s, off, 64);
        sq += __shfl_down(sq, off, 64);
    }
    __shared__ float ls[4], lq[4];
    int w = threadIdx.x >> 6;
    if ((threadIdx.x & 63) == 0) { ls[w] = s; lq[w] = sq; }
    __syncthreads();
    if (threadIdx.x == 0) {
        sums[blockIdx.x] = ls[0] + ls[1] + ls[2] + ls[3];
        sqs[blockIdx.x] = lq[0] + lq[1] + lq[2] + lq[3];
    }
}

// single block: reduce nb partials -> {scale, offset}
__global__ void reduce_final_kernel(const float* __restrict__ sums, const float* __restrict__ sqs,
                                    int nb, float n_total, const float* __restrict__ lnw,
                                    const float* __restrict__ lnb, float* __restrict__ so) {
    float s = 0.0f, sq = 0.0f;
    for (int i = threadIdx.x; i < nb; i += 1024) { s += sums[i]; sq += sqs[i]; }
#pragma unroll
    for (int off = 32; off > 0; off >>= 1) {
        s += __shfl_down(s, off, 64);
        sq += __shfl_down(sq, off, 64);
    }
    __shared__ float ls[16], lq[16];
    int w = threadIdx.x >> 6;
    if ((threadIdx.x & 63) == 0) { ls[w] = s; lq[w] = sq; }
    __syncthreads();
    if (threadIdx.x == 0) {
        float ts = 0.0f, tq = 0.0f;
        for (int i = 0; i < 16; ++i) { ts += ls[i]; tq += lq[i]; }
        float mean = ts / n_total;
        float var = tq / n_total - mean * mean;
        float scale = rsqrtf(var + 1e-5f) * lnw[0];
        so[0] = scale;
        so[1] = lnb[0] - mean * scale;
    }
}

__global__ void norm_kernel(float* __restrict__ x, int n4, const float* __restrict__ so) {
    int i = blockIdx.x * blockDim.x + threadIdx.x;
    if (i >= n4) return;
    float scale = so[0], off = so[1];
    float4* x4 = (float4*)x;
    float4 v = x4[i];
    v.x = v.x * scale + off;
    v.y = v.y * scale + off;
    v.z = v.z * scale + off;
    v.w = v.w * scale + off;
    x4[i] = v;
}

extern "C" void kernel_launch(void* const* d_in, const int* in_sizes, int n_in,
                              void* d_out, int out_size, void* d_ws, size_t ws_size,
                              hipStream_t stream) {
    const float* X   = (const float*)d_in[0];
    const int*   edg = (const int*)d_in[1];   // [2,E]: src row then dst row
    const float* W1  = (const float*)d_in[2];
    const float* b1  = (const float*)d_in[3];
    const float* W2  = (const float*)d_in[4];
    const float* b2  = (const float*)d_in[5];
    const float* lnw = (const float*)d_in[6];
    const float* lnb = (const float*)d_in[7];
    float* out = (float*)d_out;

    const int N  = in_sizes[0] / CH;   // 100000
    const int E  = in_sizes[1] / 2;    // 1600000
    const int NC = N * CH;             // 6.4M
    const int nGatherBlk = (N * CH + 255) / 256;  // 25000

    const int* srcp = edg;
    const int* dstp = edg + E;

    // workspace layout (4B units)
    int*   rs   = (int*)d_ws;                        // N  (deg -> row_start)
    int*   rank = rs + N;                            // E
    int*   col  = rank + E;                          // E
    float* dis  = (float*)(col + E);                 // N
    __hip_bfloat16* xws = (__hip_bfloat16*)(dis + N); // NC bf16
    float* h    = (float*)(xws + NC);                // NC floats
    int*   bsum = (int*)(h + NC);                    // 1024
    float* sums = (float*)(bsum + 1024);             // nGatherBlk
    float* sqs  = sums + nGatherBlk;                 // nGatherBlk
    float* so   = sqs + nGatherBlk;                  // 2 {scale, offset}

    const int B = 256;
    const int nScanBlk = (N + 1023) / 1024;          // 98

    // ---- CSR build ----
    hipMemsetAsync(rs, 0, (size_t)N * sizeof(int), stream);
    deg_rank_kernel<<<(E + B - 1) / B, B, 0, stream>>>(dstp, rs, rank, E);
    scan_block_kernel<<<nScanBlk, 1024, 0, stream>>>(rs, bsum, dis, N);
    scan_top_kernel<<<1, 1024, 0, stream>>>(bsum, nScanBlk);
    scan_add_kernel<<<(N + B - 1) / B, B, 0, stream>>>(rs, bsum, N);
    fill_csr_kernel<<<(E + B - 1) / B, B, 0, stream>>>(srcp, dstp, rs, rank, col, E);
    // rs holds row_start (exclusive); row i spans [rs[i], rs[i+1]) with rs[N]==E

    // ---- layer 1 ----
    gemm64_scaled_kernel<<<(NC + B - 1) / B, B, 0, stream>>>(X, W1, dis, xws, N);
    gather_kernel<<<nGatherBlk, B, 0, stream>>>(xws, col, rs, dis, b1, h, N, E);

    // ---- layer 2 (LN stats fused into gather epilogue) ----
    gemm64_scaled_kernel<<<(NC + B - 1) / B, B, 0, stream>>>(h, W2, dis, xws, N);
    gather_stats_kernel<<<nGatherBlk, B, 0, stream>>>(xws, col, rs, dis, b2, out, N, E, sums, sqs);

    // ---- graph layernorm ----
    reduce_final_kernel<<<1, 1024, 0, stream>>>(sums, sqs, nGatherBlk, (float)NC, lnw, lnb, so);
    norm_kernel<<<(NC / 4 + B - 1) / B, B, 0, stream>>>(out, NC / 4, so);
}